// Round 18
// baseline (117.436 us; speedup 1.0000x reference)
//
#include <hip/hip_runtime.h>
#include <hip/hip_bf16.h>
#include <cstdint>

#define EPS 1e-5f
#define NEG 0.1f

using bfrag = __attribute__((ext_vector_type(8))) short;   // 8 bf16
using f32x4 = __attribute__((ext_vector_type(4))) float;
typedef unsigned short ushort_t;

// geometry
constexpr int B_  = 4,  CIN = 64, H0 = 192, W0 = 192;
constexpr int C_  = 128, H_ = 96, W_ = 96;
constexpr int HW_ = H_ * W_;      // 9216
constexpr int HW0 = H0 * W0;      // 36864
constexpr int XS  = 194;          // padded xcl dim (1-px halo)
constexpr int TS  = 98;           // padded t1/t3 dim (1-px halo)
constexpr int VR2 = 136;          // dcn val row stride per tap-chunk (ushorts)

__device__ __forceinline__ ushort_t f2bf(float f) {
  unsigned u = __builtin_bit_cast(unsigned, f);
  u += 0x7fffu + ((u >> 16) & 1u);
  return (ushort_t)(u >> 16);
}
__device__ __forceinline__ float loF(unsigned d) {
  return __builtin_bit_cast(float, d << 16);
}
__device__ __forceinline__ float hiF(unsigned d) {
  return __builtin_bit_cast(float, d & 0xFFFF0000u);
}
__device__ __forceinline__ bfrag loadB(const ushort_t* p) {
  return *(const bfrag*)p;
}

#define MFMA4(A0, A1, B0, B1, ACC)                                             \
  ACC[0][0] = __builtin_amdgcn_mfma_f32_16x16x32_bf16(A0, B0, ACC[0][0], 0, 0, 0); \
  ACC[0][1] = __builtin_amdgcn_mfma_f32_16x16x32_bf16(A0, B1, ACC[0][1], 0, 0, 0); \
  ACC[1][0] = __builtin_amdgcn_mfma_f32_16x16x32_bf16(A1, B0, ACC[1][0], 0, 0, 0); \
  ACC[1][1] = __builtin_amdgcn_mfma_f32_16x16x32_bf16(A1, B1, ACC[1][1], 0, 0, 0);

// ---------------------------------------------------------------------------
// k_prep: weight packing + halo zeroing + x->NHWC bf16 transpose, ONE launch.
// ---------------------------------------------------------------------------
__global__ __launch_bounds__(256)
void k_prep(const float* __restrict__ x,
            const float* __restrict__ w_r1, const float* __restrict__ w_r2,
            const float* __restrict__ w_off, const float* __restrict__ w_dcn,
            const float* __restrict__ w_rs, const float* __restrict__ w_c2,
            const float* __restrict__ w_ds,
            ushort_t* __restrict__ wp_r1, ushort_t* __restrict__ wp_r2,
            ushort_t* __restrict__ wp_off, ushort_t* __restrict__ wp_dcn,
            ushort_t* __restrict__ wp_rs, ushort_t* __restrict__ wp_c2,
            ushort_t* __restrict__ wp_ds,
            ushort_t* __restrict__ xclp, ushort_t* __restrict__ t1p,
            ushort_t* __restrict__ t3p) {
  __shared__ float tile[64][65];
  int bi = blockIdx.x;
  int tid = (int)threadIdx.x;
  auto pack3w = [&](const float* w, ushort_t* wp, int O, int C, int Opad, int b0) {
    int idx = (bi - b0) * 256 + tid;
    int e = idx & 7;
    int lane = (idx >> 3) & 63;
    int fb = idx >> 9;
    int OBQ = Opad / 16;
    int obq = fb % OBQ, s = fb / OBQ;
    int lr = lane & 15, lq = lane >> 4;
    int o = obq * 16 + lr;
    int cq = s % (C / 32), tap = s / (C / 32);
    int c = cq * 32 + lq * 8 + e;
    wp[idx] = (o < O) ? f2bf(w[((size_t)o * C + c) * 9 + tap]) : (ushort_t)0;
  };
  auto pack1w = [&](const float* w, ushort_t* wp, int O, int C, int Opad, int b0) {
    int idx = (bi - b0) * 256 + tid;
    int e = idx & 7;
    int lane = (idx >> 3) & 63;
    int fb = idx >> 9;
    int OBQ = Opad / 16;
    int obq = fb % OBQ, s = fb / OBQ;
    int lr = lane & 15, lq = lane >> 4;
    int o = obq * 16 + lr;
    int c = s * 32 + lq * 8 + e;
    wp[idx] = (o < O) ? f2bf(w[(size_t)o * C + c]) : (ushort_t)0;
  };
  auto border = [&](ushort_t* buf, int N, int C, int b0) {
    int idx = (bi - b0) * 256 + tid;
    int per = 4 * N - 4;
    if (idx >= per * 4) return;
    int b = idx / per, e = idx - b * per;
    int r, s;
    if (e < N) { r = 0; s = e; }
    else if (e < 2 * N) { r = N - 1; s = e - N; }
    else if (e < 3 * N - 2) { r = e - 2 * N + 1; s = 0; }
    else { r = e - (3 * N - 2) + 1; s = N - 1; }
    uint4* p = (uint4*)(buf + ((size_t)(b * N + r) * N + s) * C);
#pragma unroll
    for (int t = 0; t < 16; ++t) { if (t < C / 8) p[t] = make_uint4(0, 0, 0, 0); }
  };
  if      (bi <  288) pack3w(w_r1,  wp_r1, 128,  64, 128, 0);
  else if (bi <  864) pack3w(w_r2,  wp_r2, 128, 128, 128, 288);
  else if (bi < 1152) pack3w(w_off, wp_off, 54, 128,  64, 864);
  else if (bi < 1728) pack3w(w_dcn, wp_dcn, 128, 128, 128, 1152);
  else if (bi < 1760) pack1w(w_rs,  wp_rs, 128,  64, 128, 1728);
  else if (bi < 1824) pack1w(w_c2,  wp_c2, 128, 128, 128, 1760);
  else if (bi < 1856) pack1w(w_ds,  wp_ds, 128,  64, 128, 1824);
  else if (bi < 1869) border(xclp, XS, 64, 1856);
  else if (bi < 1876) border(t1p, TS, 128, 1869);
  else if (bi < 1883) border(t3p, TS, 128, 1876);
  else {
    int bx = bi - 1883;
    int cx = bx % 3;
    int rem = bx / 3;
    int y = rem % 192, b = rem / 192;
    int tx = tid & 63, ty = tid >> 6;
    const float* src = x + (size_t)b * CIN * HW0 + (size_t)y * W0 + cx * 64;
#pragma unroll
    for (int r = 0; r < 16; ++r) {
      int ch = r * 4 + ty;
      tile[ch][tx] = src[(size_t)ch * HW0 + tx];
    }
    __syncthreads();
    ushort_t* dst = xclp + ((size_t)(b * XS + y + 1) * XS + cx * 64 + 1) * 64;
#pragma unroll
    for (int r = 0; r < 16; ++r) {
      int pp = r * 4 + ty;
      dst[(size_t)pp * 64 + tx] = f2bf(tile[tx][pp]);
    }
  }
}

// ---------------------------------------------------------------------------
// K1: conv3x3 s2 p1 (64->128) + BN + LReLU.  xclp -> t1p. 2 rows/block.
// ---------------------------------------------------------------------------
__global__ __launch_bounds__(256)
void k_conv1(const ushort_t* __restrict__ xclp, const ushort_t* __restrict__ wp,
             const float* __restrict__ bnp, ushort_t* __restrict__ t1p) {
  __shared__ ushort_t at[5 * 66 * 64];     // 42240 B
  int tid = threadIdx.x, lane = tid & 63, wv = tid >> 6;
  int lr = lane & 15, lq = lane >> 4, ob = wv * 32;
  int j0 = blockIdx.x * 32, i0 = blockIdx.y * 2, b = blockIdx.z;
  for (int t = tid; t < 2640; t += 256) {
    int ky = t / 528, r = t - ky * 528;
    int p = r >> 3, c8 = r & 7;
    const char* src = (const char*)(xclp +
        ((size_t)(b * XS + 2 * i0 + ky) * XS + 2 * j0) * 64) + p * 128 + c8 * 16;
    int db = ((ky * 66 + p) * 128 + c8 * 16) ^ (((p >> 1) & 7) << 4);
    *(uint4*)((char*)at + db) = *(const uint4*)src;
  }
  __syncthreads();
  f32x4 acc[2][2][2] = {};
#pragma unroll
  for (int tap = 0; tap < 9; ++tap) {
    int ky = tap / 3, kx = tap - 3 * ky;
    int pxa = 2 * lr + kx, pxb = 2 * (16 + lr) + kx;
#pragma unroll
    for (int cq = 0; cq < 2; ++cq) {
      int s = tap * 2 + cq;
      bfrag b0 = loadB(wp + (size_t)(s * 8 + wv * 2) * 512 + lane * 8);
      bfrag b1 = loadB(wp + (size_t)(s * 8 + wv * 2 + 1) * 512 + lane * 8);
#pragma unroll
      for (int r = 0; r < 2; ++r) {
        int kr = 2 * r + ky;
        bfrag a0 = *(const bfrag*)((const char*)at +
            (((kr * 66 + pxa) * 128 + cq * 64 + lq * 16) ^ (((pxa >> 1) & 7) << 4)));
        bfrag a1 = *(const bfrag*)((const char*)at +
            (((kr * 66 + pxb) * 128 + cq * 64 + lq * 16) ^ (((pxb >> 1) & 7) << 4)));
        MFMA4(a0, a1, b0, b1, acc[r]);
      }
    }
  }
#pragma unroll
  for (int r = 0; r < 2; ++r) {
    ushort_t* dst = t1p + ((size_t)(b * TS + i0 + r + 1) * TS + j0 + 1) * 128;
#pragma unroll
    for (int nf = 0; nf < 2; ++nf) {
      int o = ob + nf * 16 + lr;
      float inv = bnp[o] * rsqrtf(bnp[384 + o] + EPS);
      float bb = bnp[128 + o] - bnp[256 + o] * inv;
#pragma unroll
      for (int mf = 0; mf < 2; ++mf)
#pragma unroll
        for (int jj = 0; jj < 4; ++jj) {
          int pix = mf * 16 + 4 * lq + jj;
          float v = acc[r][mf][nf][jj] * inv + bb;
          v = v >= 0.f ? v : NEG * v;
          dst[(size_t)pix * 128 + o] = f2bf(v);
        }
    }
  }
}

// ---------------------------------------------------------------------------
// K2: conv3x3 s1 p1 (128->128)+BN + 1x1 s2 shortcut+BN, add, LReLU -> t3p
// 2 output rows/block.
// ---------------------------------------------------------------------------
__global__ __launch_bounds__(256)
void k_conv2(const ushort_t* __restrict__ t1p, const ushort_t* __restrict__ xclp,
             const ushort_t* __restrict__ wp2, const ushort_t* __restrict__ wprs,
             const float* __restrict__ bn2p, const float* __restrict__ bnsp,
             ushort_t* __restrict__ t3p) {
  __shared__ ushort_t at[4 * 34 * 128];    // 34816 B
  int tid = threadIdx.x, lane = tid & 63, wv = tid >> 6;
  int lr = lane & 15, lq = lane >> 4, ob = wv * 32;
  int j0 = blockIdx.x * 32, i0 = blockIdx.y * 2, b = blockIdx.z;
  for (int t = tid; t < 2176; t += 256) {
    int ky = t / 544, r = t - ky * 544;
    int p = r >> 4, c16 = r & 15;
    const char* src = (const char*)(t1p +
        ((size_t)(b * TS + i0 + ky) * TS + j0) * 128) + p * 256 + c16 * 16;
    int db = ((ky * 34 + p) * 256 + c16 * 16) ^ ((p & 7) << 4);
    *(uint4*)((char*)at + db) = *(const uint4*)src;
  }
  __syncthreads();
  f32x4 acc[2][2][2] = {};
  f32x4 acs[2][2][2] = {};
#pragma unroll
  for (int tap = 0; tap < 9; ++tap) {
    int ky = tap / 3, kx = tap - 3 * ky;
    int pxa = lr + kx, pxb = 16 + lr + kx;
#pragma unroll
    for (int cq = 0; cq < 4; ++cq) {
      int s = tap * 4 + cq;
      bfrag b0 = loadB(wp2 + (size_t)(s * 8 + wv * 2) * 512 + lane * 8);
      bfrag b1 = loadB(wp2 + (size_t)(s * 8 + wv * 2 + 1) * 512 + lane * 8);
#pragma unroll
      for (int r = 0; r < 2; ++r) {
        int kr = r + ky;
        bfrag a0 = *(const bfrag*)((const char*)at +
            (((kr * 34 + pxa) * 256 + cq * 64 + lq * 16) ^ ((pxa & 7) << 4)));
        bfrag a1 = *(const bfrag*)((const char*)at +
            (((kr * 34 + pxb) * 256 + cq * 64 + lq * 16) ^ ((pxb & 7) << 4)));
        MFMA4(a0, a1, b0, b1, acc[r]);
      }
    }
  }
#pragma unroll
  for (int r = 0; r < 2; ++r) {
    const ushort_t* rowp = xclp + (size_t)(b * XS + 2 * (i0 + r) + 1) * XS * 64;
    const ushort_t* pa = rowp + (size_t)(2 * (j0 + lr) + 1) * 64 + 8 * lq;
    const ushort_t* pb = rowp + (size_t)(2 * (j0 + 16 + lr) + 1) * 64 + 8 * lq;
#pragma unroll
    for (int sq = 0; sq < 2; ++sq) {
      bfrag a0 = loadB(pa + sq * 32);
      bfrag a1 = loadB(pb + sq * 32);
      bfrag b0 = loadB(wprs + (size_t)(sq * 8 + wv * 2) * 512 + lane * 8);
      bfrag b1 = loadB(wprs + (size_t)(sq * 8 + wv * 2 + 1) * 512 + lane * 8);
      MFMA4(a0, a1, b0, b1, acs[r]);
    }
  }
#pragma unroll
  for (int r = 0; r < 2; ++r) {
    ushort_t* dst = t3p + ((size_t)(b * TS + i0 + r + 1) * TS + j0 + 1) * 128;
#pragma unroll
    for (int nf = 0; nf < 2; ++nf) {
      int o = ob + nf * 16 + lr;
      float i2 = bn2p[o] * rsqrtf(bn2p[384 + o] + EPS);
      float b2 = bn2p[128 + o] - bn2p[256 + o] * i2;
      float is = bnsp[o] * rsqrtf(bnsp[384 + o] + EPS);
      float bs = bnsp[128 + o] - bnsp[256 + o] * is;
#pragma unroll
      for (int mf = 0; mf < 2; ++mf)
#pragma unroll
        for (int jj = 0; jj < 4; ++jj) {
          int pix = mf * 16 + 4 * lq + jj;
          float h = acc[r][mf][nf][jj] * i2 + b2 + acs[r][mf][nf][jj] * is + bs;
          h = h >= 0.f ? h : NEG * h;
          dst[(size_t)pix * 128 + o] = f2bf(h);
        }
    }
  }
}

// ---------------------------------------------------------------------------
// K4: DCNv2 fully fused: offset-conv + sample + contract + BN/LReLU +
//     1x1 c2 conv + 1x1 s2 residual -> out (NCHW fp32).
// 32 px/block, 512 threads (8 waves). Gather/MFMA software-pipelined via
// double-buffered 1-tap val chunks (one barrier per tap).
// ---------------------------------------------------------------------------
__global__ __launch_bounds__(512)
void k_dcn(const ushort_t* __restrict__ t3p, const ushort_t* __restrict__ wpo,
           const float* __restrict__ boff, const ushort_t* __restrict__ wp,
           const float* __restrict__ bdcn, const float* __restrict__ bnp,
           const ushort_t* __restrict__ xclp, const ushort_t* __restrict__ wpc2,
           const ushort_t* __restrict__ wpds, const float* __restrict__ bn2p,
           const float* __restrict__ bndsp, float* __restrict__ outp) {
  __shared__ char smem[26112];           // stage tile / val dbuf / ol staging
  __shared__ float aux_f[2304];          // offb_lds (8KB) then t4t [32][136]
  int tid = threadIdx.x;
  int j0 = blockIdx.x * 32, i = blockIdx.y, b = blockIdx.z;
  int lane = tid & 63, wv = tid >> 6;
  int lr = lane & 15, lq = lane >> 4;

  // ---- phase A: fused offset conv (out 32px x 64o) ----
  {
    for (int t = tid; t < 1632; t += 512) {
      int ky = t / 544, r = t - ky * 544;
      int p = r >> 4, c16b = r & 15;
      const char* src = (const char*)(t3p +
          ((size_t)(b * TS + i + ky) * TS + j0 + p) * 128) + c16b * 16;
      int db = ((ky * 34 + p) * 256 + c16b * 16) ^ ((p & 7) << 4);
      *(uint4*)(smem + db) = *(const uint4*)src;
    }
    __syncthreads();
    int ot = wv >> 1, half = wv & 1;
    f32x4 pacc = {};
#pragma unroll
    for (int s = 0; s < 36; ++s) {
      int tap = s >> 2, cq = s & 3;
      int ky = tap / 3, kx = tap - 3 * ky;
      int px = half * 16 + lr + kx;
      bfrag a0 = *(const bfrag*)(smem +
          (((ky * 34 + px) * 256 + cq * 64 + lq * 16) ^ ((px & 7) << 4)));
      bfrag b0 = loadB(wpo + (size_t)(s * 4 + ot) * 512 + lane * 8);
      pacc = __builtin_amdgcn_mfma_f32_16x16x32_bf16(a0, b0, pacc, 0, 0, 0);
    }
    int o = ot * 16 + lr;
    float bias = (o < 54) ? boff[o] : 0.f;
#pragma unroll
    for (int jj = 0; jj < 4; ++jj) {
      int px = half * 16 + 4 * lq + jj;
      aux_f[px * 64 + o] = pacc[jj] + bias;
    }
    __syncthreads();
  }

  // ---- phase 0: per-lane offset meta for pixel gq, both g ----
  int gq = tid >> 4;          // pixel 0..31
  int c16 = tid & 15;
  int gl = (gq & 3) * 16;     // group base lane within wave
  int my_b0 = 0, my_b1 = 0;
  unsigned my_w00 = 0, my_w10 = 0, my_w01 = 0, my_w11 = 0;
  if (c16 < 9) {
    int k = c16;
    int ky = k / 3, kx = k - 3 * ky;
    int j = j0 + gq;
    const float* ob_ = aux_f + gq * 64;
#pragma unroll
    for (int g = 0; g < 2; ++g) {
      int gk = g * 9 + k;
      float dy = ob_[gk];
      float dx = ob_[18 + gk];
      float ml = ob_[36 + gk];
      float mk = 1.f / (1.f + __expf(-ml));
      float py = (float)(i - 1 + ky) + dy;
      float px = (float)(j - 1 + kx) + dx;
      float fy = floorf(py), fx = floorf(px);
      float wy = py - fy, wx = px - fx;
      int y0 = (int)fy, x0 = (int)fx;
      bool yv0 = (unsigned)y0 < 96u, yv1 = (unsigned)(y0 + 1) < 96u;
      bool xv0 = (unsigned)x0 < 96u, xv1 = (unsigned)(x0 + 1) < 96u;
      float w00 = (yv0 && xv0) ? (1.f - wy) * (1.f - wx) * mk : 0.f;
      float w01 = (yv0 && xv1) ? (1.f - wy) * wx * mk : 0.f;
      float w10 = (yv1 && xv0) ? wy * (1.f - wx) * mk : 0.f;
      float w11 = (yv1 && xv1) ? wy * wx * mk : 0.f;
      int yb = min(max(y0, -1), 95), xb = min(max(x0, -1), 95);
      int bb = (((yb + 1) * TS + xb + 1) * 128 + g * 64) * 2;
      unsigned pw0 = (unsigned)f2bf(w00) | ((unsigned)f2bf(w01) << 16);
      unsigned pw1 = (unsigned)f2bf(w10) | ((unsigned)f2bf(w11) << 16);
      if (g == 0) { my_b0 = bb; my_w00 = pw0; my_w10 = pw1; }
      else        { my_b1 = bb; my_w01 = pw0; my_w11 = pw1; }
    }
  }
  __syncthreads();   // stage tile + offb consumed

  // ---- phases 1+2: 9 tap-chunks, double-buffered, 1 barrier per tap ----
  ushort_t* buf0 = (ushort_t*)smem;            // [32][VR2] = 8704 B
  ushort_t* buf1 = (ushort_t*)(smem + 8704);   // [32][VR2]
  const char* imgb = (const char*)(t3p + (size_t)b * TS * TS * 128) + c16 * 8;
  int ob = wv * 16;
  f32x4 acc0 = {}, acc1 = {};

  auto gather_tap = [&](ushort_t* buf, int k) {
    char* vrow = (char*)buf + gq * (VR2 * 2) + c16 * 8;
#pragma unroll
    for (int g = 0; g < 2; ++g) {
      int gb = __shfl(g == 0 ? my_b0 : my_b1, gl + k, 64);
      unsigned w0 = (unsigned)__shfl((int)(g == 0 ? my_w00 : my_w01), gl + k, 64);
      unsigned w1 = (unsigned)__shfl((int)(g == 0 ? my_w10 : my_w11), gl + k, 64);
      const char* pA = imgb + gb;
      uint2 d00 = *(const uint2*)pA;
      uint2 d01 = *(const uint2*)(pA + 256);
      uint2 d10 = *(const uint2*)(pA + TS * 256);
      uint2 d11 = *(const uint2*)(pA + TS * 256 + 256);
      float w00 = loF(w0), w01 = hiF(w0);
      float w10 = loF(w1), w11 = hiF(w1);
      unsigned o2[2];
#pragma unroll
      for (int t = 0; t < 2; ++t) {
        unsigned e00 = ((const unsigned*)&d00)[t];
        unsigned e01 = ((const unsigned*)&d01)[t];
        unsigned e10 = ((const unsigned*)&d10)[t];
        unsigned e11 = ((const unsigned*)&d11)[t];
        float slo = loF(e00) * w00 + loF(e01) * w01 + loF(e10) * w10 + loF(e11) * w11;
        float shi = hiF(e00) * w00 + hiF(e01) * w01 + hiF(e10) * w10 + hiF(e11) * w11;
        unsigned u0 = __builtin_bit_cast(unsigned, slo) + 0x8000u;
        unsigned u1 = __builtin_bit_cast(unsigned, shi) + 0x8000u;
        o2[t] = __builtin_amdgcn_perm(u1, u0, 0x07060302u);
      }
      *(uint2*)(vrow + g * 128) = make_uint2(o2[0], o2[1]);
    }
  };

  gather_tap(buf0, 0);
  __syncthreads();
#pragma unroll
  for (int c = 0; c < 9; ++c) {
    if (c < 8) gather_tap((c & 1) ? buf0 : buf1, c + 1);
    ushort_t* vb = (c & 1) ? buf1 : buf0;
#pragma unroll
    for (int sl = 0; sl < 4; ++sl) {
      int s = c * 4 + sl;
      bfrag a0 = *(const bfrag*)&vb[lr * VR2 + 32 * sl + 8 * lq];
      bfrag a1 = *(const bfrag*)&vb[(16 + lr) * VR2 + 32 * sl + 8 * lq];
      bfrag b0 = loadB(wp + (size_t)(s * 8 + wv) * 512 + lane * 8);
      acc0 = __builtin_amdgcn_mfma_f32_16x16x32_bf16(a0, b0, acc0, 0, 0, 0);
      acc1 = __builtin_amdgcn_mfma_f32_16x16x32_bf16(a1, b0, acc1, 0, 0, 0);
    }
    __syncthreads();
  }

  // ---- t4 = BN+LReLU(dcn) staged in LDS (aux region, stride 136) ----
  ushort_t* t4t = (ushort_t*)aux_f;      // [32][136] = 8704 B
  {
    int o = ob + lr;
    float inv = bnp[o] * rsqrtf(bnp[384 + o] + EPS);
    float bb = bnp[128 + o] - bnp[256 + o] * inv;
    float bd = bdcn[o];
#pragma unroll
    for (int jj = 0; jj < 4; ++jj) {
      int p0 = 4 * lq + jj;
      float r0 = (acc0[jj] + bd) * inv + bb;
      r0 = r0 >= 0.f ? r0 : NEG * r0;
      t4t[p0 * 136 + o] = f2bf(r0);
      float r1 = (acc1[jj] + bd) * inv + bb;
      r1 = r1 >= 0.f ? r1 : NEG * r1;
      t4t[(16 + p0) * 136 + o] = f2bf(r1);
    }
  }
  __syncthreads();

  // ---- fused final: 1x1 c2 (A from t4t LDS) + 1x1 s2 residual ----
  f32x4 f0 = {}, f1 = {}, s0 = {}, s1 = {};
#pragma unroll
  for (int s = 0; s < 4; ++s) {
    bfrag a0 = *(const bfrag*)&t4t[lr * 136 + s * 32 + 8 * lq];
    bfrag a1 = *(const bfrag*)&t4t[(16 + lr) * 136 + s * 32 + 8 * lq];
    bfrag b0 = loadB(wpc2 + (size_t)(s * 8 + wv) * 512 + lane * 8);
    f0 = __builtin_amdgcn_mfma_f32_16x16x32_bf16(a0, b0, f0, 0, 0, 0);
    f1 = __builtin_amdgcn_mfma_f32_16x16x32_bf16(a1, b0, f1, 0, 0, 0);
  }
  {
    const ushort_t* rowx = xclp + (size_t)(b * XS + 2 * i + 1) * XS * 64;
    const ushort_t* pa = rowx + (size_t)(2 * (j0 + lr) + 1) * 64 + 8 * lq;
    const ushort_t* pb = rowx + (size_t)(2 * (j0 + 16 + lr) + 1) * 64 + 8 * lq;
#pragma unroll
    for (int s = 0; s < 2; ++s) {
      bfrag a0 = loadB(pa + s * 32);
      bfrag a1 = loadB(pb + s * 32);
      bfrag b0 = loadB(wpds + (size_t)(s * 8 + wv) * 512 + lane * 8);
      s0 = __builtin_amdgcn_mfma_f32_16x16x32_bf16(a0, b0, s0, 0, 0, 0);
      s1 = __builtin_amdgcn_mfma_f32_16x16x32_bf16(a1, b0, s1, 0, 0, 0);
    }
  }
  float* ol = (float*)smem;              // [128][36] = 18432 B (val dead)
  {
    int o = ob + lr;
    float i2 = bn2p[o] * rsqrtf(bn2p[384 + o] + EPS);
    float b2 = bn2p[128 + o] - bn2p[256 + o] * i2;
    float id = bndsp[o] * rsqrtf(bndsp[384 + o] + EPS);
    float bd2 = bndsp[128 + o] - bndsp[256 + o] * id;
#pragma unroll
    for (int jj = 0; jj < 4; ++jj) {
      int p0 = 4 * lq + jj;
      float h0 = f0[jj] * i2 + b2;
      h0 = h0 >= 0.f ? h0 : NEG * h0;
      ol[o * 36 + p0] = s0[jj] * id + bd2 + h0;
      float h1 = f1[jj] * i2 + b2;
      h1 = h1 >= 0.f ? h1 : NEG * h1;
      ol[o * 36 + 16 + p0] = s1[jj] * id + bd2 + h1;
    }
  }
  __syncthreads();
#pragma unroll
  for (int r = 0; r < 2; ++r) {
    int idx = r * 512 + tid;             // 1024 float4 tasks
    int o = idx >> 3, p4 = idx & 7;
    f32x4 v = *(const f32x4*)&ol[o * 36 + p4 * 4];
    *(f32x4*)&outp[((size_t)(b * C_ + o) * H_ + i) * W_ + j0 + p4 * 4] = v;
  }
}

// ---------------------------------------------------------------------------
extern "C" void kernel_launch(void* const* d_in, const int* in_sizes, int n_in,
                              void* d_out, int out_size, void* d_ws, size_t ws_size,
                              hipStream_t stream) {
  const float* x     = (const float*)d_in[0];
  const float* w_r1  = (const float*)d_in[1];
  const float* bn_r1 = (const float*)d_in[2];
  const float* w_r2  = (const float*)d_in[3];
  const float* bn_r2 = (const float*)d_in[4];
  const float* w_rs  = (const float*)d_in[5];
  const float* bn_rs = (const float*)d_in[6];
  const float* w_off = (const float*)d_in[7];
  const float* b_off = (const float*)d_in[8];
  const float* w_dcn = (const float*)d_in[9];
  const float* b_dcn = (const float*)d_in[10];
  const float* bn1   = (const float*)d_in[11];
  const float* w_c2  = (const float*)d_in[12];
  const float* bn2   = (const float*)d_in[13];
  const float* w_ds  = (const float*)d_in[14];
  const float* bn_ds = (const float*)d_in[15];
  float* out = (float*)d_out;

  // workspace layout (ushort elems)
  ushort_t* base  = (ushort_t*)d_ws;
  ushort_t* xclp  = base;                        // 9634816
  ushort_t* t1p   = base + 9634816;              // 4917248
  ushort_t* t3p   = base + 14552064;             // 4917248
  ushort_t* wp_r1 = base + 19469312;             // 73728
  ushort_t* wp_r2 = wp_r1 + 73728;               // 147456
  ushort_t* wp_off= wp_r2 + 147456;              // 73728
  ushort_t* wp_dcn= wp_off + 73728;              // 147456
  ushort_t* wp_rs = wp_dcn + 147456;             // 8192
  ushort_t* wp_c2 = wp_rs + 8192;                // 16384
  ushort_t* wp_ds = wp_c2 + 16384;               // 8192

  k_prep<<<4187, 256, 0, stream>>>(x, w_r1, w_r2, w_off, w_dcn, w_rs, w_c2,
                                   w_ds, wp_r1, wp_r2, wp_off, wp_dcn, wp_rs,
                                   wp_c2, wp_ds, xclp, t1p, t3p);

  k_conv1<<<dim3(3, 48, 4), 256, 0, stream>>>(xclp, wp_r1, bn_r1, t1p);
  k_conv2<<<dim3(3, 48, 4), 256, 0, stream>>>(t1p, xclp, wp_r2, wp_rs, bn_r2, bn_rs, t3p);
  k_dcn  <<<dim3(3, 96, 4), 512, 0, stream>>>(t3p, wp_off, b_off, wp_dcn, b_dcn, bn1,
                                              xclp, wp_c2, wp_ds, bn2, bn_ds, out);
}

// Round 19
// 110.060 us; speedup vs baseline: 1.0670x; 1.0670x over previous
//
#include <hip/hip_runtime.h>
#include <hip/hip_bf16.h>
#include <cstdint>

#define EPS 1e-5f
#define NEG 0.1f

using bfrag = __attribute__((ext_vector_type(8))) short;   // 8 bf16
using f32x4 = __attribute__((ext_vector_type(4))) float;
typedef unsigned short ushort_t;

// geometry
constexpr int B_  = 4,  CIN = 64, H0 = 192, W0 = 192;
constexpr int C_  = 128, H_ = 96, W_ = 96;
constexpr int HW_ = H_ * W_;      // 9216
constexpr int HW0 = H0 * W0;      // 36864
constexpr int XS  = 194;          // padded xcl dim (1-px halo)
constexpr int TS  = 98;           // padded t1/t3 dim (1-px halo)
constexpr int VROW = 392;         // dcn val row stride per K-chunk (ushorts)

__device__ __forceinline__ ushort_t f2bf(float f) {
  unsigned u = __builtin_bit_cast(unsigned, f);
  u += 0x7fffu + ((u >> 16) & 1u);
  return (ushort_t)(u >> 16);
}
__device__ __forceinline__ float loF(unsigned d) {
  return __builtin_bit_cast(float, d << 16);
}
__device__ __forceinline__ float hiF(unsigned d) {
  return __builtin_bit_cast(float, d & 0xFFFF0000u);
}
__device__ __forceinline__ bfrag loadB(const ushort_t* p) {
  return *(const bfrag*)p;
}

#define MFMA4(A0, A1, B0, B1, ACC)                                             \
  ACC[0][0] = __builtin_amdgcn_mfma_f32_16x16x32_bf16(A0, B0, ACC[0][0], 0, 0, 0); \
  ACC[0][1] = __builtin_amdgcn_mfma_f32_16x16x32_bf16(A0, B1, ACC[0][1], 0, 0, 0); \
  ACC[1][0] = __builtin_amdgcn_mfma_f32_16x16x32_bf16(A1, B0, ACC[1][0], 0, 0, 0); \
  ACC[1][1] = __builtin_amdgcn_mfma_f32_16x16x32_bf16(A1, B1, ACC[1][1], 0, 0, 0);

// ---------------------------------------------------------------------------
// k_prep: weight packing + halo zeroing + x->NHWC bf16 transpose, ONE launch.
// ---------------------------------------------------------------------------
__global__ __launch_bounds__(256)
void k_prep(const float* __restrict__ x,
            const float* __restrict__ w_r1, const float* __restrict__ w_r2,
            const float* __restrict__ w_off, const float* __restrict__ w_dcn,
            const float* __restrict__ w_rs, const float* __restrict__ w_c2,
            const float* __restrict__ w_ds,
            ushort_t* __restrict__ wp_r1, ushort_t* __restrict__ wp_r2,
            ushort_t* __restrict__ wp_off, ushort_t* __restrict__ wp_dcn,
            ushort_t* __restrict__ wp_rs, ushort_t* __restrict__ wp_c2,
            ushort_t* __restrict__ wp_ds,
            ushort_t* __restrict__ xclp, ushort_t* __restrict__ t1p,
            ushort_t* __restrict__ t3p) {
  __shared__ float tile[64][65];
  int bi = blockIdx.x;
  int tid = (int)threadIdx.x;
  auto pack3w = [&](const float* w, ushort_t* wp, int O, int C, int Opad, int b0) {
    int idx = (bi - b0) * 256 + tid;
    int e = idx & 7;
    int lane = (idx >> 3) & 63;
    int fb = idx >> 9;
    int OBQ = Opad / 16;
    int obq = fb % OBQ, s = fb / OBQ;
    int lr = lane & 15, lq = lane >> 4;
    int o = obq * 16 + lr;
    int cq = s % (C / 32), tap = s / (C / 32);
    int c = cq * 32 + lq * 8 + e;
    wp[idx] = (o < O) ? f2bf(w[((size_t)o * C + c) * 9 + tap]) : (ushort_t)0;
  };
  auto pack1w = [&](const float* w, ushort_t* wp, int O, int C, int Opad, int b0) {
    int idx = (bi - b0) * 256 + tid;
    int e = idx & 7;
    int lane = (idx >> 3) & 63;
    int fb = idx >> 9;
    int OBQ = Opad / 16;
    int obq = fb % OBQ, s = fb / OBQ;
    int lr = lane & 15, lq = lane >> 4;
    int o = obq * 16 + lr;
    int c = s * 32 + lq * 8 + e;
    wp[idx] = (o < O) ? f2bf(w[(size_t)o * C + c]) : (ushort_t)0;
  };
  auto border = [&](ushort_t* buf, int N, int C, int b0) {
    int idx = (bi - b0) * 256 + tid;
    int per = 4 * N - 4;
    if (idx >= per * 4) return;
    int b = idx / per, e = idx - b * per;
    int r, s;
    if (e < N) { r = 0; s = e; }
    else if (e < 2 * N) { r = N - 1; s = e - N; }
    else if (e < 3 * N - 2) { r = e - 2 * N + 1; s = 0; }
    else { r = e - (3 * N - 2) + 1; s = N - 1; }
    uint4* p = (uint4*)(buf + ((size_t)(b * N + r) * N + s) * C);
#pragma unroll
    for (int t = 0; t < 16; ++t) { if (t < C / 8) p[t] = make_uint4(0, 0, 0, 0); }
  };
  if      (bi <  288) pack3w(w_r1,  wp_r1, 128,  64, 128, 0);
  else if (bi <  864) pack3w(w_r2,  wp_r2, 128, 128, 128, 288);
  else if (bi < 1152) pack3w(w_off, wp_off, 54, 128,  64, 864);
  else if (bi < 1728) pack3w(w_dcn, wp_dcn, 128, 128, 128, 1152);
  else if (bi < 1760) pack1w(w_rs,  wp_rs, 128,  64, 128, 1728);
  else if (bi < 1824) pack1w(w_c2,  wp_c2, 128, 128, 128, 1760);
  else if (bi < 1856) pack1w(w_ds,  wp_ds, 128,  64, 128, 1824);
  else if (bi < 1869) border(xclp, XS, 64, 1856);
  else if (bi < 1876) border(t1p, TS, 128, 1869);
  else if (bi < 1883) border(t3p, TS, 128, 1876);
  else {
    int bx = bi - 1883;
    int cx = bx % 3;
    int rem = bx / 3;
    int y = rem % 192, b = rem / 192;
    int tx = tid & 63, ty = tid >> 6;
    const float* src = x + (size_t)b * CIN * HW0 + (size_t)y * W0 + cx * 64;
#pragma unroll
    for (int r = 0; r < 16; ++r) {
      int ch = r * 4 + ty;
      tile[ch][tx] = src[(size_t)ch * HW0 + tx];
    }
    __syncthreads();
    ushort_t* dst = xclp + ((size_t)(b * XS + y + 1) * XS + cx * 64 + 1) * 64;
#pragma unroll
    for (int r = 0; r < 16; ++r) {
      int pp = r * 4 + ty;
      dst[(size_t)pp * 64 + tx] = f2bf(tile[tx][pp]);
    }
  }
}

// ---------------------------------------------------------------------------
// K1: conv3x3 s2 p1 (64->128) + BN + LReLU.  xclp -> t1p. 2 rows/block.
// ---------------------------------------------------------------------------
__global__ __launch_bounds__(256)
void k_conv1(const ushort_t* __restrict__ xclp, const ushort_t* __restrict__ wp,
             const float* __restrict__ bnp, ushort_t* __restrict__ t1p) {
  __shared__ ushort_t at[5 * 66 * 64];     // 42240 B
  int tid = threadIdx.x, lane = tid & 63, wv = tid >> 6;
  int lr = lane & 15, lq = lane >> 4, ob = wv * 32;
  int j0 = blockIdx.x * 32, i0 = blockIdx.y * 2, b = blockIdx.z;
  for (int t = tid; t < 2640; t += 256) {
    int ky = t / 528, r = t - ky * 528;
    int p = r >> 3, c8 = r & 7;
    const char* src = (const char*)(xclp +
        ((size_t)(b * XS + 2 * i0 + ky) * XS + 2 * j0) * 64) + p * 128 + c8 * 16;
    int db = ((ky * 66 + p) * 128 + c8 * 16) ^ (((p >> 1) & 7) << 4);
    *(uint4*)((char*)at + db) = *(const uint4*)src;
  }
  __syncthreads();
  f32x4 acc[2][2][2] = {};
#pragma unroll
  for (int tap = 0; tap < 9; ++tap) {
    int ky = tap / 3, kx = tap - 3 * ky;
    int pxa = 2 * lr + kx, pxb = 2 * (16 + lr) + kx;
#pragma unroll
    for (int cq = 0; cq < 2; ++cq) {
      int s = tap * 2 + cq;
      bfrag b0 = loadB(wp + (size_t)(s * 8 + wv * 2) * 512 + lane * 8);
      bfrag b1 = loadB(wp + (size_t)(s * 8 + wv * 2 + 1) * 512 + lane * 8);
#pragma unroll
      for (int r = 0; r < 2; ++r) {
        int kr = 2 * r + ky;
        bfrag a0 = *(const bfrag*)((const char*)at +
            (((kr * 66 + pxa) * 128 + cq * 64 + lq * 16) ^ (((pxa >> 1) & 7) << 4)));
        bfrag a1 = *(const bfrag*)((const char*)at +
            (((kr * 66 + pxb) * 128 + cq * 64 + lq * 16) ^ (((pxb >> 1) & 7) << 4)));
        MFMA4(a0, a1, b0, b1, acc[r]);
      }
    }
  }
#pragma unroll
  for (int r = 0; r < 2; ++r) {
    ushort_t* dst = t1p + ((size_t)(b * TS + i0 + r + 1) * TS + j0 + 1) * 128;
#pragma unroll
    for (int nf = 0; nf < 2; ++nf) {
      int o = ob + nf * 16 + lr;
      float inv = bnp[o] * rsqrtf(bnp[384 + o] + EPS);
      float bb = bnp[128 + o] - bnp[256 + o] * inv;
#pragma unroll
      for (int mf = 0; mf < 2; ++mf)
#pragma unroll
        for (int jj = 0; jj < 4; ++jj) {
          int pix = mf * 16 + 4 * lq + jj;
          float v = acc[r][mf][nf][jj] * inv + bb;
          v = v >= 0.f ? v : NEG * v;
          dst[(size_t)pix * 128 + o] = f2bf(v);
        }
    }
  }
}

// ---------------------------------------------------------------------------
// K2: conv3x3 s1 p1 (128->128)+BN + 1x1 s2 shortcut+BN, add, LReLU -> t3p
// 2 output rows/block.
// ---------------------------------------------------------------------------
__global__ __launch_bounds__(256)
void k_conv2(const ushort_t* __restrict__ t1p, const ushort_t* __restrict__ xclp,
             const ushort_t* __restrict__ wp2, const ushort_t* __restrict__ wprs,
             const float* __restrict__ bn2p, const float* __restrict__ bnsp,
             ushort_t* __restrict__ t3p) {
  __shared__ ushort_t at[4 * 34 * 128];    // 34816 B
  int tid = threadIdx.x, lane = tid & 63, wv = tid >> 6;
  int lr = lane & 15, lq = lane >> 4, ob = wv * 32;
  int j0 = blockIdx.x * 32, i0 = blockIdx.y * 2, b = blockIdx.z;
  for (int t = tid; t < 2176; t += 256) {
    int ky = t / 544, r = t - ky * 544;
    int p = r >> 4, c16 = r & 15;
    const char* src = (const char*)(t1p +
        ((size_t)(b * TS + i0 + ky) * TS + j0) * 128) + p * 256 + c16 * 16;
    int db = ((ky * 34 + p) * 256 + c16 * 16) ^ ((p & 7) << 4);
    *(uint4*)((char*)at + db) = *(const uint4*)src;
  }
  __syncthreads();
  f32x4 acc[2][2][2] = {};
  f32x4 acs[2][2][2] = {};
#pragma unroll
  for (int tap = 0; tap < 9; ++tap) {
    int ky = tap / 3, kx = tap - 3 * ky;
    int pxa = lr + kx, pxb = 16 + lr + kx;
#pragma unroll
    for (int cq = 0; cq < 4; ++cq) {
      int s = tap * 4 + cq;
      bfrag b0 = loadB(wp2 + (size_t)(s * 8 + wv * 2) * 512 + lane * 8);
      bfrag b1 = loadB(wp2 + (size_t)(s * 8 + wv * 2 + 1) * 512 + lane * 8);
#pragma unroll
      for (int r = 0; r < 2; ++r) {
        int kr = r + ky;
        bfrag a0 = *(const bfrag*)((const char*)at +
            (((kr * 34 + pxa) * 256 + cq * 64 + lq * 16) ^ ((pxa & 7) << 4)));
        bfrag a1 = *(const bfrag*)((const char*)at +
            (((kr * 34 + pxb) * 256 + cq * 64 + lq * 16) ^ ((pxb & 7) << 4)));
        MFMA4(a0, a1, b0, b1, acc[r]);
      }
    }
  }
#pragma unroll
  for (int r = 0; r < 2; ++r) {
    const ushort_t* rowp = xclp + (size_t)(b * XS + 2 * (i0 + r) + 1) * XS * 64;
    const ushort_t* pa = rowp + (size_t)(2 * (j0 + lr) + 1) * 64 + 8 * lq;
    const ushort_t* pb = rowp + (size_t)(2 * (j0 + 16 + lr) + 1) * 64 + 8 * lq;
#pragma unroll
    for (int sq = 0; sq < 2; ++sq) {
      bfrag a0 = loadB(pa + sq * 32);
      bfrag a1 = loadB(pb + sq * 32);
      bfrag b0 = loadB(wprs + (size_t)(sq * 8 + wv * 2) * 512 + lane * 8);
      bfrag b1 = loadB(wprs + (size_t)(sq * 8 + wv * 2 + 1) * 512 + lane * 8);
      MFMA4(a0, a1, b0, b1, acs[r]);
    }
  }
#pragma unroll
  for (int r = 0; r < 2; ++r) {
    ushort_t* dst = t3p + ((size_t)(b * TS + i0 + r + 1) * TS + j0 + 1) * 128;
#pragma unroll
    for (int nf = 0; nf < 2; ++nf) {
      int o = ob + nf * 16 + lr;
      float i2 = bn2p[o] * rsqrtf(bn2p[384 + o] + EPS);
      float b2 = bn2p[128 + o] - bn2p[256 + o] * i2;
      float is = bnsp[o] * rsqrtf(bnsp[384 + o] + EPS);
      float bs = bnsp[128 + o] - bnsp[256 + o] * is;
#pragma unroll
      for (int mf = 0; mf < 2; ++mf)
#pragma unroll
        for (int jj = 0; jj < 4; ++jj) {
          int pix = mf * 16 + 4 * lq + jj;
          float h = acc[r][mf][nf][jj] * i2 + b2 + acs[r][mf][nf][jj] * is + bs;
          h = h >= 0.f ? h : NEG * h;
          dst[(size_t)pix * 128 + o] = f2bf(h);
        }
    }
  }
}

// ---------------------------------------------------------------------------
// K4: DCNv2 fully fused, 256 threads (4 waves), 32 px/block, 26.5KB LDS ->
// 6 blocks/CU so the whole 1152-block grid is co-resident (no round tail).
// smem arena aliasing: stage(26112) -> offb(8192) -> val(25088) ->
// t4t(8704) + ol(18432 @ +8704).
// ---------------------------------------------------------------------------
__global__ __launch_bounds__(256, 6)
void k_dcn(const ushort_t* __restrict__ t3p, const ushort_t* __restrict__ wpo,
           const float* __restrict__ boff, const ushort_t* __restrict__ wp,
           const float* __restrict__ bdcn, const float* __restrict__ bnp,
           const ushort_t* __restrict__ xclp, const ushort_t* __restrict__ wpc2,
           const ushort_t* __restrict__ wpds, const float* __restrict__ bn2p,
           const float* __restrict__ bndsp, float* __restrict__ outp) {
  __shared__ char smem[27136];
  int tid = threadIdx.x;
  int j0 = blockIdx.x * 32, i = blockIdx.y, b = blockIdx.z;
  int lane = tid & 63, wv = tid >> 6;        // wv 0..3
  int lr = lane & 15, lq = lane >> 4;

  // ---- phase A: offset conv. stage 3x34x128 bf16 ----
  for (int t = tid; t < 1632; t += 256) {
    int ky = t / 544, r = t - ky * 544;
    int p = r >> 4, c16b = r & 15;
    const char* src = (const char*)(t3p +
        ((size_t)(b * TS + i + ky) * TS + j0 + p) * 128) + c16b * 16;
    int db = ((ky * 34 + p) * 256 + c16b * 16) ^ ((p & 7) << 4);
    *(uint4*)(smem + db) = *(const uint4*)src;
  }
  __syncthreads();
  // wave wv -> o-tile wv (16 o), both px halves
  f32x4 pa0 = {}, pa1 = {};
#pragma unroll
  for (int s = 0; s < 36; ++s) {
    int tap = s >> 2, cq = s & 3;
    int ky = tap / 3, kx = tap - 3 * ky;
    int px0 = lr + kx, px1 = 16 + lr + kx;
    bfrag a0 = *(const bfrag*)(smem +
        (((ky * 34 + px0) * 256 + cq * 64 + lq * 16) ^ ((px0 & 7) << 4)));
    bfrag a1 = *(const bfrag*)(smem +
        (((ky * 34 + px1) * 256 + cq * 64 + lq * 16) ^ ((px1 & 7) << 4)));
    bfrag b0 = loadB(wpo + (size_t)(s * 4 + wv) * 512 + lane * 8);
    pa0 = __builtin_amdgcn_mfma_f32_16x16x32_bf16(a0, b0, pa0, 0, 0, 0);
    pa1 = __builtin_amdgcn_mfma_f32_16x16x32_bf16(a1, b0, pa1, 0, 0, 0);
  }
  __syncthreads();                      // stage consumed
  float* offb_l = (float*)smem;         // [32][64] = 8192 B
  {
    int o = wv * 16 + lr;
    float bias = (o < 54) ? boff[o] : 0.f;
#pragma unroll
    for (int jj = 0; jj < 4; ++jj) {
      offb_l[(4 * lq + jj) * 64 + o] = pa0[jj] + bias;
      offb_l[(16 + 4 * lq + jj) * 64 + o] = pa1[jj] + bias;
    }
  }
  __syncthreads();

  // ---- phase 0: per-lane offset meta; group gq owns pixels gq, gq+16 ----
  int gq = tid >> 4;          // 0..15
  int c16 = tid & 15;
  int gl = (gq & 3) * 16;     // group base lane within wave
  int my_b[2][2] = {};
  unsigned my_w0[2][2] = {}, my_w1[2][2] = {};
  if (c16 < 9) {
    int k = c16;
    int ky = k / 3, kx = k - 3 * ky;
#pragma unroll
    for (int px2 = 0; px2 < 2; ++px2) {
      int pixel = gq + 16 * px2;
      int j = j0 + pixel;
      const float* ob_ = offb_l + pixel * 64;
#pragma unroll
      for (int g = 0; g < 2; ++g) {
        int gk = g * 9 + k;
        float dy = ob_[gk];
        float dx = ob_[18 + gk];
        float ml = ob_[36 + gk];
        float mk = 1.f / (1.f + __expf(-ml));
        float py = (float)(i - 1 + ky) + dy;
        float px = (float)(j - 1 + kx) + dx;
        float fy = floorf(py), fx = floorf(px);
        float wy = py - fy, wx = px - fx;
        int y0 = (int)fy, x0 = (int)fx;
        bool yv0 = (unsigned)y0 < 96u, yv1 = (unsigned)(y0 + 1) < 96u;
        bool xv0 = (unsigned)x0 < 96u, xv1 = (unsigned)(x0 + 1) < 96u;
        float w00 = (yv0 && xv0) ? (1.f - wy) * (1.f - wx) * mk : 0.f;
        float w01 = (yv0 && xv1) ? (1.f - wy) * wx * mk : 0.f;
        float w10 = (yv1 && xv0) ? wy * (1.f - wx) * mk : 0.f;
        float w11 = (yv1 && xv1) ? wy * wx * mk : 0.f;
        int yb = min(max(y0, -1), 95), xb = min(max(x0, -1), 95);
        my_b[px2][g] = (((yb + 1) * TS + xb + 1) * 128 + g * 64) * 2;
        my_w0[px2][g] = (unsigned)f2bf(w00) | ((unsigned)f2bf(w01) << 16);
        my_w1[px2][g] = (unsigned)f2bf(w10) | ((unsigned)f2bf(w11) << 16);
      }
    }
  }
  __syncthreads();                      // offb consumed

  // ---- phases 1+2: 3 K-chunks of 3 taps ----
  ushort_t* val = (ushort_t*)smem;      // [32][VROW] = 25088 B
  const char* imgb = (const char*)(t3p + (size_t)b * TS * TS * 128) + c16 * 8;
  f32x4 acc[2][2] = {};                 // [px_half][o_sub]; o = wv*32+os*16
#pragma unroll
  for (int c = 0; c < 3; ++c) {
#pragma unroll
    for (int px2 = 0; px2 < 2; ++px2) {
      char* vrow = (char*)val + (gq + 16 * px2) * (VROW * 2) + c16 * 8;
#pragma unroll
      for (int g = 0; g < 2; ++g) {
#pragma unroll
        for (int kc = 0; kc < 3; ++kc) {
          int k = 3 * c + kc;
          int gb = __shfl(my_b[px2][g], gl + k, 64);
          unsigned w0 = (unsigned)__shfl((int)my_w0[px2][g], gl + k, 64);
          unsigned w1 = (unsigned)__shfl((int)my_w1[px2][g], gl + k, 64);
          const char* pA = imgb + gb;
          uint2 d00 = *(const uint2*)pA;
          uint2 d01 = *(const uint2*)(pA + 256);
          uint2 d10 = *(const uint2*)(pA + TS * 256);
          uint2 d11 = *(const uint2*)(pA + TS * 256 + 256);
          float w00 = loF(w0), w01 = hiF(w0);
          float w10 = loF(w1), w11 = hiF(w1);
          unsigned o2[2];
#pragma unroll
          for (int t = 0; t < 2; ++t) {
            unsigned e00 = ((const unsigned*)&d00)[t];
            unsigned e01 = ((const unsigned*)&d01)[t];
            unsigned e10 = ((const unsigned*)&d10)[t];
            unsigned e11 = ((const unsigned*)&d11)[t];
            float slo = loF(e00) * w00 + loF(e01) * w01 + loF(e10) * w10 + loF(e11) * w11;
            float shi = hiF(e00) * w00 + hiF(e01) * w01 + hiF(e10) * w10 + hiF(e11) * w11;
            unsigned u0 = __builtin_bit_cast(unsigned, slo) + 0x8000u;
            unsigned u1 = __builtin_bit_cast(unsigned, shi) + 0x8000u;
            o2[t] = __builtin_amdgcn_perm(u1, u0, 0x07060302u);
          }
          *(uint2*)(vrow + kc * 256 + g * 128) = make_uint2(o2[0], o2[1]);
        }
      }
    }
    __syncthreads();
#pragma unroll
    for (int sl = 0; sl < 12; ++sl) {
      int s = c * 12 + sl;
      bfrag a0 = *(const bfrag*)&val[lr * VROW + 32 * sl + 8 * lq];
      bfrag a1 = *(const bfrag*)&val[(16 + lr) * VROW + 32 * sl + 8 * lq];
      bfrag b0 = loadB(wp + (size_t)(s * 8 + 2 * wv) * 512 + lane * 8);
      bfrag b1 = loadB(wp + (size_t)(s * 8 + 2 * wv + 1) * 512 + lane * 8);
      MFMA4(a0, a1, b0, b1, acc);
    }
    __syncthreads();
  }

  // ---- t4 = BN+LReLU(dcn) -> LDS [32][136] at smem[0:8704] ----
  ushort_t* t4t = (ushort_t*)smem;
#pragma unroll
  for (int os = 0; os < 2; ++os) {
    int o = wv * 32 + os * 16 + lr;
    float inv = bnp[o] * rsqrtf(bnp[384 + o] + EPS);
    float bb = bnp[128 + o] - bnp[256 + o] * inv;
    float bd = bdcn[o];
#pragma unroll
    for (int jj = 0; jj < 4; ++jj) {
      int p0 = 4 * lq + jj;
      float r0 = (acc[0][os][jj] + bd) * inv + bb;
      r0 = r0 >= 0.f ? r0 : NEG * r0;
      t4t[p0 * 136 + o] = f2bf(r0);
      float r1 = (acc[1][os][jj] + bd) * inv + bb;
      r1 = r1 >= 0.f ? r1 : NEG * r1;
      t4t[(16 + p0) * 136 + o] = f2bf(r1);
    }
  }
  __syncthreads();

  // ---- fused final: 1x1 c2 (A from t4t) + 1x1 s2 residual ----
  f32x4 fc[2][2] = {}, sr[2][2] = {};
#pragma unroll
  for (int s = 0; s < 4; ++s) {
    bfrag a0 = *(const bfrag*)&t4t[lr * 136 + s * 32 + 8 * lq];
    bfrag a1 = *(const bfrag*)&t4t[(16 + lr) * 136 + s * 32 + 8 * lq];
    bfrag b0 = loadB(wpc2 + (size_t)(s * 8 + 2 * wv) * 512 + lane * 8);
    bfrag b1 = loadB(wpc2 + (size_t)(s * 8 + 2 * wv + 1) * 512 + lane * 8);
    MFMA4(a0, a1, b0, b1, fc);
  }
  {
    const ushort_t* rowx = xclp + (size_t)(b * XS + 2 * i + 1) * XS * 64;
    const ushort_t* pa = rowx + (size_t)(2 * (j0 + lr) + 1) * 64 + 8 * lq;
    const ushort_t* pb = rowx + (size_t)(2 * (j0 + 16 + lr) + 1) * 64 + 8 * lq;
#pragma unroll
    for (int s = 0; s < 2; ++s) {
      bfrag a0 = loadB(pa + s * 32);
      bfrag a1 = loadB(pb + s * 32);
      bfrag b0 = loadB(wpds + (size_t)(s * 8 + 2 * wv) * 512 + lane * 8);
      bfrag b1 = loadB(wpds + (size_t)(s * 8 + 2 * wv + 1) * 512 + lane * 8);
      MFMA4(a0, a1, b0, b1, sr);
    }
  }
  float* ol = (float*)(smem + 8704);    // [128][36] = 18432 B
#pragma unroll
  for (int os = 0; os < 2; ++os) {
    int o = wv * 32 + os * 16 + lr;
    float i2 = bn2p[o] * rsqrtf(bn2p[384 + o] + EPS);
    float b2 = bn2p[128 + o] - bn2p[256 + o] * i2;
    float id = bndsp[o] * rsqrtf(bndsp[384 + o] + EPS);
    float bd2 = bndsp[128 + o] - bndsp[256 + o] * id;
#pragma unroll
    for (int jj = 0; jj < 4; ++jj) {
      int p0 = 4 * lq + jj;
      float h0 = fc[0][os][jj] * i2 + b2;
      h0 = h0 >= 0.f ? h0 : NEG * h0;
      ol[o * 36 + p0] = sr[0][os][jj] * id + bd2 + h0;
      float h1 = fc[1][os][jj] * i2 + b2;
      h1 = h1 >= 0.f ? h1 : NEG * h1;
      ol[o * 36 + 16 + p0] = sr[1][os][jj] * id + bd2 + h1;
    }
  }
  __syncthreads();
#pragma unroll
  for (int r = 0; r < 4; ++r) {
    int idx = r * 256 + tid;             // 1024 float4 tasks
    int o = idx >> 3, p4 = idx & 7;
    f32x4 v = *(const f32x4*)&ol[o * 36 + p4 * 4];
    *(f32x4*)&outp[((size_t)(b * C_ + o) * H_ + i) * W_ + j0 + p4 * 4] = v;
  }
}

// ---------------------------------------------------------------------------
extern "C" void kernel_launch(void* const* d_in, const int* in_sizes, int n_in,
                              void* d_out, int out_size, void* d_ws, size_t ws_size,
                              hipStream_t stream) {
  const float* x     = (const float*)d_in[0];
  const float* w_r1  = (const float*)d_in[1];
  const float* bn_r1 = (const float*)d_in[2];
  const float* w_r2  = (const float*)d_in[3];
  const float* bn_r2 = (const float*)d_in[4];
  const float* w_rs  = (const float*)d_in[5];
  const float* bn_rs = (const float*)d_in[6];
  const float* w_off = (const float*)d_in[7];
  const float* b_off = (const float*)d_in[8];
  const float* w_dcn = (const float*)d_in[9];
  const float* b_dcn = (const float*)d_in[10];
  const float* bn1   = (const float*)d_in[11];
  const float* w_c2  = (const float*)d_in[12];
  const float* bn2   = (const float*)d_in[13];
  const float* w_ds  = (const float*)d_in[14];
  const float* bn_ds = (const float*)d_in[15];
  float* out = (float*)d_out;

  // workspace layout (ushort elems)
  ushort_t* base  = (ushort_t*)d_ws;
  ushort_t* xclp  = base;                        // 9634816
  ushort_t* t1p   = base + 9634816;              // 4917248
  ushort_t* t3p   = base + 14552064;             // 4917248
  ushort_t* wp_r1 = base + 19469312;             // 73728
  ushort_t* wp_r2 = wp_r1 + 73728;               // 147456
  ushort_t* wp_off= wp_r2 + 147456;              // 73728
  ushort_t* wp_dcn= wp_off + 73728;              // 147456
  ushort_t* wp_rs = wp_dcn + 147456;             // 8192
  ushort_t* wp_c2 = wp_rs + 8192;                // 16384
  ushort_t* wp_ds = wp_c2 + 16384;               // 8192

  k_prep<<<4187, 256, 0, stream>>>(x, w_r1, w_r2, w_off, w_dcn, w_rs, w_c2,
                                   w_ds, wp_r1, wp_r2, wp_off, wp_dcn, wp_rs,
                                   wp_c2, wp_ds, xclp, t1p, t3p);

  k_conv1<<<dim3(3, 48, 4), 256, 0, stream>>>(xclp, wp_r1, bn_r1, t1p);
  k_conv2<<<dim3(3, 48, 4), 256, 0, stream>>>(t1p, xclp, wp_r2, wp_rs, bn_r2, bn_rs, t3p);
  k_dcn  <<<dim3(3, 96, 4), 256, 0, stream>>>(t3p, wp_off, b_off, wp_dcn, b_dcn, bn1,
                                              xclp, wp_c2, wp_ds, bn2, bn_ds, out);
}

// Round 20
// 107.364 us; speedup vs baseline: 1.0938x; 1.0251x over previous
//
#include <hip/hip_runtime.h>
#include <hip/hip_bf16.h>
#include <cstdint>

#define EPS 1e-5f
#define NEG 0.1f

using bfrag = __attribute__((ext_vector_type(8))) short;   // 8 bf16
using f32x4 = __attribute__((ext_vector_type(4))) float;
typedef unsigned short ushort_t;

// geometry
constexpr int B_  = 4,  CIN = 64, H0 = 192, W0 = 192;
constexpr int C_  = 128, H_ = 96, W_ = 96;
constexpr int HW_ = H_ * W_;      // 9216
constexpr int HW0 = H0 * W0;      // 36864
constexpr int XS  = 194;          // padded xcl dim (1-px halo)
constexpr int TS  = 98;           // padded t1/t3 dim (1-px halo)
constexpr int VROW = 392;         // dcn val row stride per K-chunk (ushorts)

__device__ __forceinline__ ushort_t f2bf(float f) {
  unsigned u = __builtin_bit_cast(unsigned, f);
  u += 0x7fffu + ((u >> 16) & 1u);
  return (ushort_t)(u >> 16);
}
__device__ __forceinline__ float loF(unsigned d) {
  return __builtin_bit_cast(float, d << 16);
}
__device__ __forceinline__ float hiF(unsigned d) {
  return __builtin_bit_cast(float, d & 0xFFFF0000u);
}
__device__ __forceinline__ bfrag loadB(const ushort_t* p) {
  return *(const bfrag*)p;
}

#define MFMA4(A0, A1, B0, B1, ACC)                                             \
  ACC[0][0] = __builtin_amdgcn_mfma_f32_16x16x32_bf16(A0, B0, ACC[0][0], 0, 0, 0); \
  ACC[0][1] = __builtin_amdgcn_mfma_f32_16x16x32_bf16(A0, B1, ACC[0][1], 0, 0, 0); \
  ACC[1][0] = __builtin_amdgcn_mfma_f32_16x16x32_bf16(A1, B0, ACC[1][0], 0, 0, 0); \
  ACC[1][1] = __builtin_amdgcn_mfma_f32_16x16x32_bf16(A1, B1, ACC[1][1], 0, 0, 0);

// ---------------------------------------------------------------------------
// k_prep: weight packing + halo zeroing + x->NHWC bf16 transpose, ONE launch.
// ---------------------------------------------------------------------------
__global__ __launch_bounds__(256)
void k_prep(const float* __restrict__ x,
            const float* __restrict__ w_r1, const float* __restrict__ w_r2,
            const float* __restrict__ w_off, const float* __restrict__ w_dcn,
            const float* __restrict__ w_rs, const float* __restrict__ w_c2,
            const float* __restrict__ w_ds,
            ushort_t* __restrict__ wp_r1, ushort_t* __restrict__ wp_r2,
            ushort_t* __restrict__ wp_off, ushort_t* __restrict__ wp_dcn,
            ushort_t* __restrict__ wp_rs, ushort_t* __restrict__ wp_c2,
            ushort_t* __restrict__ wp_ds,
            ushort_t* __restrict__ xclp, ushort_t* __restrict__ t1p,
            ushort_t* __restrict__ t3p) {
  __shared__ float tile[64][65];
  int bi = blockIdx.x;
  int tid = (int)threadIdx.x;
  auto pack3w = [&](const float* w, ushort_t* wp, int O, int C, int Opad, int b0) {
    int idx = (bi - b0) * 256 + tid;
    int e = idx & 7;
    int lane = (idx >> 3) & 63;
    int fb = idx >> 9;
    int OBQ = Opad / 16;
    int obq = fb % OBQ, s = fb / OBQ;
    int lr = lane & 15, lq = lane >> 4;
    int o = obq * 16 + lr;
    int cq = s % (C / 32), tap = s / (C / 32);
    int c = cq * 32 + lq * 8 + e;
    wp[idx] = (o < O) ? f2bf(w[((size_t)o * C + c) * 9 + tap]) : (ushort_t)0;
  };
  auto pack1w = [&](const float* w, ushort_t* wp, int O, int C, int Opad, int b0) {
    int idx = (bi - b0) * 256 + tid;
    int e = idx & 7;
    int lane = (idx >> 3) & 63;
    int fb = idx >> 9;
    int OBQ = Opad / 16;
    int obq = fb % OBQ, s = fb / OBQ;
    int lr = lane & 15, lq = lane >> 4;
    int o = obq * 16 + lr;
    int c = s * 32 + lq * 8 + e;
    wp[idx] = (o < O) ? f2bf(w[(size_t)o * C + c]) : (ushort_t)0;
  };
  auto border = [&](ushort_t* buf, int N, int C, int b0) {
    int idx = (bi - b0) * 256 + tid;
    int per = 4 * N - 4;
    if (idx >= per * 4) return;
    int b = idx / per, e = idx - b * per;
    int r, s;
    if (e < N) { r = 0; s = e; }
    else if (e < 2 * N) { r = N - 1; s = e - N; }
    else if (e < 3 * N - 2) { r = e - 2 * N + 1; s = 0; }
    else { r = e - (3 * N - 2) + 1; s = N - 1; }
    uint4* p = (uint4*)(buf + ((size_t)(b * N + r) * N + s) * C);
#pragma unroll
    for (int t = 0; t < 16; ++t) { if (t < C / 8) p[t] = make_uint4(0, 0, 0, 0); }
  };
  if      (bi <  288) pack3w(w_r1,  wp_r1, 128,  64, 128, 0);
  else if (bi <  864) pack3w(w_r2,  wp_r2, 128, 128, 128, 288);
  else if (bi < 1152) pack3w(w_off, wp_off, 54, 128,  64, 864);
  else if (bi < 1728) pack3w(w_dcn, wp_dcn, 128, 128, 128, 1152);
  else if (bi < 1760) pack1w(w_rs,  wp_rs, 128,  64, 128, 1728);
  else if (bi < 1824) pack1w(w_c2,  wp_c2, 128, 128, 128, 1760);
  else if (bi < 1856) pack1w(w_ds,  wp_ds, 128,  64, 128, 1824);
  else if (bi < 1869) border(xclp, XS, 64, 1856);
  else if (bi < 1876) border(t1p, TS, 128, 1869);
  else if (bi < 1883) border(t3p, TS, 128, 1876);
  else {
    int bx = bi - 1883;
    int cx = bx % 3;
    int rem = bx / 3;
    int y = rem % 192, b = rem / 192;
    int tx = tid & 63, ty = tid >> 6;
    const float* src = x + (size_t)b * CIN * HW0 + (size_t)y * W0 + cx * 64;
#pragma unroll
    for (int r = 0; r < 16; ++r) {
      int ch = r * 4 + ty;
      tile[ch][tx] = src[(size_t)ch * HW0 + tx];
    }
    __syncthreads();
    ushort_t* dst = xclp + ((size_t)(b * XS + y + 1) * XS + cx * 64 + 1) * 64;
#pragma unroll
    for (int r = 0; r < 16; ++r) {
      int pp = r * 4 + ty;
      dst[(size_t)pp * 64 + tx] = f2bf(tile[tx][pp]);
    }
  }
}

// ---------------------------------------------------------------------------
// K1: conv3x3 s2 p1 (64->128) + BN + LReLU.  xclp -> t1p. 2 rows/block.
// ---------------------------------------------------------------------------
__global__ __launch_bounds__(256)
void k_conv1(const ushort_t* __restrict__ xclp, const ushort_t* __restrict__ wp,
             const float* __restrict__ bnp, ushort_t* __restrict__ t1p) {
  __shared__ ushort_t at[5 * 66 * 64];     // 42240 B
  int tid = threadIdx.x, lane = tid & 63, wv = tid >> 6;
  int lr = lane & 15, lq = lane >> 4, ob = wv * 32;
  int j0 = blockIdx.x * 32, i0 = blockIdx.y * 2, b = blockIdx.z;
  for (int t = tid; t < 2640; t += 256) {
    int ky = t / 528, r = t - ky * 528;
    int p = r >> 3, c8 = r & 7;
    const char* src = (const char*)(xclp +
        ((size_t)(b * XS + 2 * i0 + ky) * XS + 2 * j0) * 64) + p * 128 + c8 * 16;
    int db = ((ky * 66 + p) * 128 + c8 * 16) ^ (((p >> 1) & 7) << 4);
    *(uint4*)((char*)at + db) = *(const uint4*)src;
  }
  __syncthreads();
  f32x4 acc[2][2][2] = {};
#pragma unroll
  for (int tap = 0; tap < 9; ++tap) {
    int ky = tap / 3, kx = tap - 3 * ky;
    int pxa = 2 * lr + kx, pxb = 2 * (16 + lr) + kx;
#pragma unroll
    for (int cq = 0; cq < 2; ++cq) {
      int s = tap * 2 + cq;
      bfrag b0 = loadB(wp + (size_t)(s * 8 + wv * 2) * 512 + lane * 8);
      bfrag b1 = loadB(wp + (size_t)(s * 8 + wv * 2 + 1) * 512 + lane * 8);
#pragma unroll
      for (int r = 0; r < 2; ++r) {
        int kr = 2 * r + ky;
        bfrag a0 = *(const bfrag*)((const char*)at +
            (((kr * 66 + pxa) * 128 + cq * 64 + lq * 16) ^ (((pxa >> 1) & 7) << 4)));
        bfrag a1 = *(const bfrag*)((const char*)at +
            (((kr * 66 + pxb) * 128 + cq * 64 + lq * 16) ^ (((pxb >> 1) & 7) << 4)));
        MFMA4(a0, a1, b0, b1, acc[r]);
      }
    }
  }
#pragma unroll
  for (int r = 0; r < 2; ++r) {
    ushort_t* dst = t1p + ((size_t)(b * TS + i0 + r + 1) * TS + j0 + 1) * 128;
#pragma unroll
    for (int nf = 0; nf < 2; ++nf) {
      int o = ob + nf * 16 + lr;
      float inv = bnp[o] * rsqrtf(bnp[384 + o] + EPS);
      float bb = bnp[128 + o] - bnp[256 + o] * inv;
#pragma unroll
      for (int mf = 0; mf < 2; ++mf)
#pragma unroll
        for (int jj = 0; jj < 4; ++jj) {
          int pix = mf * 16 + 4 * lq + jj;
          float v = acc[r][mf][nf][jj] * inv + bb;
          v = v >= 0.f ? v : NEG * v;
          dst[(size_t)pix * 128 + o] = f2bf(v);
        }
    }
  }
}

// ---------------------------------------------------------------------------
// K2: conv3x3 s1 p1 (128->128)+BN + 1x1 s2 shortcut+BN, add, LReLU -> t3p
// 2 output rows/block.
// ---------------------------------------------------------------------------
__global__ __launch_bounds__(256)
void k_conv2(const ushort_t* __restrict__ t1p, const ushort_t* __restrict__ xclp,
             const ushort_t* __restrict__ wp2, const ushort_t* __restrict__ wprs,
             const float* __restrict__ bn2p, const float* __restrict__ bnsp,
             ushort_t* __restrict__ t3p) {
  __shared__ ushort_t at[4 * 34 * 128];    // 34816 B
  int tid = threadIdx.x, lane = tid & 63, wv = tid >> 6;
  int lr = lane & 15, lq = lane >> 4, ob = wv * 32;
  int j0 = blockIdx.x * 32, i0 = blockIdx.y * 2, b = blockIdx.z;
  for (int t = tid; t < 2176; t += 256) {
    int ky = t / 544, r = t - ky * 544;
    int p = r >> 4, c16 = r & 15;
    const char* src = (const char*)(t1p +
        ((size_t)(b * TS + i0 + ky) * TS + j0) * 128) + p * 256 + c16 * 16;
    int db = ((ky * 34 + p) * 256 + c16 * 16) ^ ((p & 7) << 4);
    *(uint4*)((char*)at + db) = *(const uint4*)src;
  }
  __syncthreads();
  f32x4 acc[2][2][2] = {};
  f32x4 acs[2][2][2] = {};
#pragma unroll
  for (int tap = 0; tap < 9; ++tap) {
    int ky = tap / 3, kx = tap - 3 * ky;
    int pxa = lr + kx, pxb = 16 + lr + kx;
#pragma unroll
    for (int cq = 0; cq < 4; ++cq) {
      int s = tap * 4 + cq;
      bfrag b0 = loadB(wp2 + (size_t)(s * 8 + wv * 2) * 512 + lane * 8);
      bfrag b1 = loadB(wp2 + (size_t)(s * 8 + wv * 2 + 1) * 512 + lane * 8);
#pragma unroll
      for (int r = 0; r < 2; ++r) {
        int kr = r + ky;
        bfrag a0 = *(const bfrag*)((const char*)at +
            (((kr * 34 + pxa) * 256 + cq * 64 + lq * 16) ^ ((pxa & 7) << 4)));
        bfrag a1 = *(const bfrag*)((const char*)at +
            (((kr * 34 + pxb) * 256 + cq * 64 + lq * 16) ^ ((pxb & 7) << 4)));
        MFMA4(a0, a1, b0, b1, acc[r]);
      }
    }
  }
#pragma unroll
  for (int r = 0; r < 2; ++r) {
    const ushort_t* rowp = xclp + (size_t)(b * XS + 2 * (i0 + r) + 1) * XS * 64;
    const ushort_t* pa = rowp + (size_t)(2 * (j0 + lr) + 1) * 64 + 8 * lq;
    const ushort_t* pb = rowp + (size_t)(2 * (j0 + 16 + lr) + 1) * 64 + 8 * lq;
#pragma unroll
    for (int sq = 0; sq < 2; ++sq) {
      bfrag a0 = loadB(pa + sq * 32);
      bfrag a1 = loadB(pb + sq * 32);
      bfrag b0 = loadB(wprs + (size_t)(sq * 8 + wv * 2) * 512 + lane * 8);
      bfrag b1 = loadB(wprs + (size_t)(sq * 8 + wv * 2 + 1) * 512 + lane * 8);
      MFMA4(a0, a1, b0, b1, acs[r]);
    }
  }
#pragma unroll
  for (int r = 0; r < 2; ++r) {
    ushort_t* dst = t3p + ((size_t)(b * TS + i0 + r + 1) * TS + j0 + 1) * 128;
#pragma unroll
    for (int nf = 0; nf < 2; ++nf) {
      int o = ob + nf * 16 + lr;
      float i2 = bn2p[o] * rsqrtf(bn2p[384 + o] + EPS);
      float b2 = bn2p[128 + o] - bn2p[256 + o] * i2;
      float is = bnsp[o] * rsqrtf(bnsp[384 + o] + EPS);
      float bs = bnsp[128 + o] - bnsp[256 + o] * is;
#pragma unroll
      for (int mf = 0; mf < 2; ++mf)
#pragma unroll
        for (int jj = 0; jj < 4; ++jj) {
          int pix = mf * 16 + 4 * lq + jj;
          float h = acc[r][mf][nf][jj] * i2 + b2 + acs[r][mf][nf][jj] * is + bs;
          h = h >= 0.f ? h : NEG * h;
          dst[(size_t)pix * 128 + o] = f2bf(h);
        }
    }
  }
}

// ---------------------------------------------------------------------------
// K4: DCNv2 fully fused (r19 interior), 256 threads, 32 px/block,
// 1D grid 1152 with XCD band swizzle: each XCD owns a contiguous 48-row band
// so gather reads hit its private L2.
// ---------------------------------------------------------------------------
__global__ __launch_bounds__(256, 6)
void k_dcn(const ushort_t* __restrict__ t3p, const ushort_t* __restrict__ wpo,
           const float* __restrict__ boff, const ushort_t* __restrict__ wp,
           const float* __restrict__ bdcn, const float* __restrict__ bnp,
           const ushort_t* __restrict__ xclp, const ushort_t* __restrict__ wpc2,
           const ushort_t* __restrict__ wpds, const float* __restrict__ bn2p,
           const float* __restrict__ bndsp, float* __restrict__ outp) {
  __shared__ char smem[27136];
  int tid = threadIdx.x;
  // XCD band swizzle (nwg = 1152 = 8 * 144)
  int bid = blockIdx.x;
  int lin = (bid & 7) * 144 + (bid >> 3);
  int jx = lin % 3;
  int rem = lin / 3;
  int i = rem % 96, b = rem / 96;
  int j0 = jx * 32;
  int lane = tid & 63, wv = tid >> 6;        // wv 0..3
  int lr = lane & 15, lq = lane >> 4;

  // ---- phase A: offset conv. stage 3x34x128 bf16 ----
  for (int t = tid; t < 1632; t += 256) {
    int ky = t / 544, r = t - ky * 544;
    int p = r >> 4, c16b = r & 15;
    const char* src = (const char*)(t3p +
        ((size_t)(b * TS + i + ky) * TS + j0 + p) * 128) + c16b * 16;
    int db = ((ky * 34 + p) * 256 + c16b * 16) ^ ((p & 7) << 4);
    *(uint4*)(smem + db) = *(const uint4*)src;
  }
  __syncthreads();
  f32x4 pa0 = {}, pa1 = {};
#pragma unroll
  for (int s = 0; s < 36; ++s) {
    int tap = s >> 2, cq = s & 3;
    int ky = tap / 3, kx = tap - 3 * ky;
    int px0 = lr + kx, px1 = 16 + lr + kx;
    bfrag a0 = *(const bfrag*)(smem +
        (((ky * 34 + px0) * 256 + cq * 64 + lq * 16) ^ ((px0 & 7) << 4)));
    bfrag a1 = *(const bfrag*)(smem +
        (((ky * 34 + px1) * 256 + cq * 64 + lq * 16) ^ ((px1 & 7) << 4)));
    bfrag b0 = loadB(wpo + (size_t)(s * 4 + wv) * 512 + lane * 8);
    pa0 = __builtin_amdgcn_mfma_f32_16x16x32_bf16(a0, b0, pa0, 0, 0, 0);
    pa1 = __builtin_amdgcn_mfma_f32_16x16x32_bf16(a1, b0, pa1, 0, 0, 0);
  }
  __syncthreads();                      // stage consumed
  float* offb_l = (float*)smem;         // [32][64] = 8192 B
  {
    int o = wv * 16 + lr;
    float bias = (o < 54) ? boff[o] : 0.f;
#pragma unroll
    for (int jj = 0; jj < 4; ++jj) {
      offb_l[(4 * lq + jj) * 64 + o] = pa0[jj] + bias;
      offb_l[(16 + 4 * lq + jj) * 64 + o] = pa1[jj] + bias;
    }
  }
  __syncthreads();

  // ---- phase 0: per-lane offset meta; group gq owns pixels gq, gq+16 ----
  int gq = tid >> 4;          // 0..15
  int c16 = tid & 15;
  int gl = (gq & 3) * 16;     // group base lane within wave
  int my_b[2][2] = {};
  unsigned my_w0[2][2] = {}, my_w1[2][2] = {};
  if (c16 < 9) {
    int k = c16;
    int ky = k / 3, kx = k - 3 * ky;
#pragma unroll
    for (int px2 = 0; px2 < 2; ++px2) {
      int pixel = gq + 16 * px2;
      int j = j0 + pixel;
      const float* ob_ = offb_l + pixel * 64;
#pragma unroll
      for (int g = 0; g < 2; ++g) {
        int gk = g * 9 + k;
        float dy = ob_[gk];
        float dx = ob_[18 + gk];
        float ml = ob_[36 + gk];
        float mk = 1.f / (1.f + __expf(-ml));
        float py = (float)(i - 1 + ky) + dy;
        float px = (float)(j - 1 + kx) + dx;
        float fy = floorf(py), fx = floorf(px);
        float wy = py - fy, wx = px - fx;
        int y0 = (int)fy, x0 = (int)fx;
        bool yv0 = (unsigned)y0 < 96u, yv1 = (unsigned)(y0 + 1) < 96u;
        bool xv0 = (unsigned)x0 < 96u, xv1 = (unsigned)(x0 + 1) < 96u;
        float w00 = (yv0 && xv0) ? (1.f - wy) * (1.f - wx) * mk : 0.f;
        float w01 = (yv0 && xv1) ? (1.f - wy) * wx * mk : 0.f;
        float w10 = (yv1 && xv0) ? wy * (1.f - wx) * mk : 0.f;
        float w11 = (yv1 && xv1) ? wy * wx * mk : 0.f;
        int yb = min(max(y0, -1), 95), xb = min(max(x0, -1), 95);
        my_b[px2][g] = (((yb + 1) * TS + xb + 1) * 128 + g * 64) * 2;
        my_w0[px2][g] = (unsigned)f2bf(w00) | ((unsigned)f2bf(w01) << 16);
        my_w1[px2][g] = (unsigned)f2bf(w10) | ((unsigned)f2bf(w11) << 16);
      }
    }
  }
  __syncthreads();                      // offb consumed

  // ---- phases 1+2: 3 K-chunks of 3 taps ----
  ushort_t* val = (ushort_t*)smem;      // [32][VROW] = 25088 B
  const char* imgb = (const char*)(t3p + (size_t)b * TS * TS * 128) + c16 * 8;
  f32x4 acc[2][2] = {};                 // [px_half][o_sub]; o = wv*32+os*16
#pragma unroll
  for (int c = 0; c < 3; ++c) {
#pragma unroll
    for (int px2 = 0; px2 < 2; ++px2) {
      char* vrow = (char*)val + (gq + 16 * px2) * (VROW * 2) + c16 * 8;
#pragma unroll
      for (int g = 0; g < 2; ++g) {
#pragma unroll
        for (int kc = 0; kc < 3; ++kc) {
          int k = 3 * c + kc;
          int gb = __shfl(my_b[px2][g], gl + k, 64);
          unsigned w0 = (unsigned)__shfl((int)my_w0[px2][g], gl + k, 64);
          unsigned w1 = (unsigned)__shfl((int)my_w1[px2][g], gl + k, 64);
          const char* pA = imgb + gb;
          uint2 d00 = *(const uint2*)pA;
          uint2 d01 = *(const uint2*)(pA + 256);
          uint2 d10 = *(const uint2*)(pA + TS * 256);
          uint2 d11 = *(const uint2*)(pA + TS * 256 + 256);
          float w00 = loF(w0), w01 = hiF(w0);
          float w10 = loF(w1), w11 = hiF(w1);
          unsigned o2[2];
#pragma unroll
          for (int t = 0; t < 2; ++t) {
            unsigned e00 = ((const unsigned*)&d00)[t];
            unsigned e01 = ((const unsigned*)&d01)[t];
            unsigned e10 = ((const unsigned*)&d10)[t];
            unsigned e11 = ((const unsigned*)&d11)[t];
            float slo = loF(e00) * w00 + loF(e01) * w01 + loF(e10) * w10 + loF(e11) * w11;
            float shi = hiF(e00) * w00 + hiF(e01) * w01 + hiF(e10) * w10 + hiF(e11) * w11;
            unsigned u0 = __builtin_bit_cast(unsigned, slo) + 0x8000u;
            unsigned u1 = __builtin_bit_cast(unsigned, shi) + 0x8000u;
            o2[t] = __builtin_amdgcn_perm(u1, u0, 0x07060302u);
          }
          *(uint2*)(vrow + kc * 256 + g * 128) = make_uint2(o2[0], o2[1]);
        }
      }
    }
    __syncthreads();
#pragma unroll
    for (int sl = 0; sl < 12; ++sl) {
      int s = c * 12 + sl;
      bfrag a0 = *(const bfrag*)&val[lr * VROW + 32 * sl + 8 * lq];
      bfrag a1 = *(const bfrag*)&val[(16 + lr) * VROW + 32 * sl + 8 * lq];
      bfrag b0 = loadB(wp + (size_t)(s * 8 + 2 * wv) * 512 + lane * 8);
      bfrag b1 = loadB(wp + (size_t)(s * 8 + 2 * wv + 1) * 512 + lane * 8);
      MFMA4(a0, a1, b0, b1, acc);
    }
    __syncthreads();
  }

  // ---- t4 = BN+LReLU(dcn) -> LDS [32][136] at smem[0:8704] ----
  ushort_t* t4t = (ushort_t*)smem;
#pragma unroll
  for (int os = 0; os < 2; ++os) {
    int o = wv * 32 + os * 16 + lr;
    float inv = bnp[o] * rsqrtf(bnp[384 + o] + EPS);
    float bb = bnp[128 + o] - bnp[256 + o] * inv;
    float bd = bdcn[o];
#pragma unroll
    for (int jj = 0; jj < 4; ++jj) {
      int p0 = 4 * lq + jj;
      float r0 = (acc[0][os][jj] + bd) * inv + bb;
      r0 = r0 >= 0.f ? r0 : NEG * r0;
      t4t[p0 * 136 + o] = f2bf(r0);
      float r1 = (acc[1][os][jj] + bd) * inv + bb;
      r1 = r1 >= 0.f ? r1 : NEG * r1;
      t4t[(16 + p0) * 136 + o] = f2bf(r1);
    }
  }
  __syncthreads();

  // ---- fused final: 1x1 c2 (A from t4t) + 1x1 s2 residual ----
  f32x4 fc[2][2] = {}, sr[2][2] = {};
#pragma unroll
  for (int s = 0; s < 4; ++s) {
    bfrag a0 = *(const bfrag*)&t4t[lr * 136 + s * 32 + 8 * lq];
    bfrag a1 = *(const bfrag*)&t4t[(16 + lr) * 136 + s * 32 + 8 * lq];
    bfrag b0 = loadB(wpc2 + (size_t)(s * 8 + 2 * wv) * 512 + lane * 8);
    bfrag b1 = loadB(wpc2 + (size_t)(s * 8 + 2 * wv + 1) * 512 + lane * 8);
    MFMA4(a0, a1, b0, b1, fc);
  }
  {
    const ushort_t* rowx = xclp + (size_t)(b * XS + 2 * i + 1) * XS * 64;
    const ushort_t* pa = rowx + (size_t)(2 * (j0 + lr) + 1) * 64 + 8 * lq;
    const ushort_t* pb = rowx + (size_t)(2 * (j0 + 16 + lr) + 1) * 64 + 8 * lq;
#pragma unroll
    for (int s = 0; s < 2; ++s) {
      bfrag a0 = loadB(pa + s * 32);
      bfrag a1 = loadB(pb + s * 32);
      bfrag b0 = loadB(wpds + (size_t)(s * 8 + 2 * wv) * 512 + lane * 8);
      bfrag b1 = loadB(wpds + (size_t)(s * 8 + 2 * wv + 1) * 512 + lane * 8);
      MFMA4(a0, a1, b0, b1, sr);
    }
  }
  float* ol = (float*)(smem + 8704);    // [128][36] = 18432 B
#pragma unroll
  for (int os = 0; os < 2; ++os) {
    int o = wv * 32 + os * 16 + lr;
    float i2 = bn2p[o] * rsqrtf(bn2p[384 + o] + EPS);
    float b2 = bn2p[128 + o] - bn2p[256 + o] * i2;
    float id = bndsp[o] * rsqrtf(bndsp[384 + o] + EPS);
    float bd2 = bndsp[128 + o] - bndsp[256 + o] * id;
#pragma unroll
    for (int jj = 0; jj < 4; ++jj) {
      int p0 = 4 * lq + jj;
      float h0 = fc[0][os][jj] * i2 + b2;
      h0 = h0 >= 0.f ? h0 : NEG * h0;
      ol[o * 36 + p0] = sr[0][os][jj] * id + bd2 + h0;
      float h1 = fc[1][os][jj] * i2 + b2;
      h1 = h1 >= 0.f ? h1 : NEG * h1;
      ol[o * 36 + 16 + p0] = sr[1][os][jj] * id + bd2 + h1;
    }
  }
  __syncthreads();
#pragma unroll
  for (int r = 0; r < 4; ++r) {
    int idx = r * 256 + tid;             // 1024 float4 tasks
    int o = idx >> 3, p4 = idx & 7;
    f32x4 v = *(const f32x4*)&ol[o * 36 + p4 * 4];
    *(f32x4*)&outp[((size_t)(b * C_ + o) * H_ + i) * W_ + j0 + p4 * 4] = v;
  }
}

// ---------------------------------------------------------------------------
extern "C" void kernel_launch(void* const* d_in, const int* in_sizes, int n_in,
                              void* d_out, int out_size, void* d_ws, size_t ws_size,
                              hipStream_t stream) {
  const float* x     = (const float*)d_in[0];
  const float* w_r1  = (const float*)d_in[1];
  const float* bn_r1 = (const float*)d_in[2];
  const float* w_r2  = (const float*)d_in[3];
  const float* bn_r2 = (const float*)d_in[4];
  const float* w_rs  = (const float*)d_in[5];
  const float* bn_rs = (const float*)d_in[6];
  const float* w_off = (const float*)d_in[7];
  const float* b_off = (const float*)d_in[8];
  const float* w_dcn = (const float*)d_in[9];
  const float* b_dcn = (const float*)d_in[10];
  const float* bn1   = (const float*)d_in[11];
  const float* w_c2  = (const float*)d_in[12];
  const float* bn2   = (const float*)d_in[13];
  const float* w_ds  = (const float*)d_in[14];
  const float* bn_ds = (const float*)d_in[15];
  float* out = (float*)d_out;

  // workspace layout (ushort elems)
  ushort_t* base  = (ushort_t*)d_ws;
  ushort_t* xclp  = base;                        // 9634816
  ushort_t* t1p   = base + 9634816;              // 4917248
  ushort_t* t3p   = base + 14552064;             // 4917248
  ushort_t* wp_r1 = base + 19469312;             // 73728
  ushort_t* wp_r2 = wp_r1 + 73728;               // 147456
  ushort_t* wp_off= wp_r2 + 147456;              // 73728
  ushort_t* wp_dcn= wp_off + 73728;              // 147456
  ushort_t* wp_rs = wp_dcn + 147456;             // 8192
  ushort_t* wp_c2 = wp_rs + 8192;                // 16384
  ushort_t* wp_ds = wp_c2 + 16384;               // 8192

  k_prep<<<4187, 256, 0, stream>>>(x, w_r1, w_r2, w_off, w_dcn, w_rs, w_c2,
                                   w_ds, wp_r1, wp_r2, wp_off, wp_dcn, wp_rs,
                                   wp_c2, wp_ds, xclp, t1p, t3p);

  k_conv1<<<dim3(3, 48, 4), 256, 0, stream>>>(xclp, wp_r1, bn_r1, t1p);
  k_conv2<<<dim3(3, 48, 4), 256, 0, stream>>>(t1p, xclp, wp_r2, wp_rs, bn_r2, bn_rs, t3p);
  k_dcn  <<<1152, 256, 0, stream>>>(t3p, wp_off, b_off, wp_dcn, b_dcn, bn1,
                                    xclp, wp_c2, wp_ds, bn2, bn_ds, out);
}